// Round 1
// 111.578 us; speedup vs baseline: 1.0435x; 1.0435x over previous
//
#include <hip/hip_runtime.h>
#include <stdint.h>

#define N_NODES 100000
#define N_ELEM4 50000          // nibble-packed element table: 4 bits/node
#define N_EDGES 3200000
#define N_ELEMS 10
#define N_PAIRS (N_ELEMS * N_ELEMS)

#define NB 256                 // node buckets
#define NPB 391                // nodes per bucket: 256*391 = 100096 >= 100000
#define SCAT_THREADS 1024      // 16 waves/block; 2 blocks/CU (53.6 KB LDS each)
#define NBLK 512               // scatter blocks
#define EPB 6256               // edges per block: 512*6256 = 3,203,072 >= 3.2M
#define NGROUPS (EPB / 4)      // 1564 float4-groups per block
#define NG4 (N_EDGES / 4)      // 800000 float4-groups total
#define PREP_BLOCKS 196        // 196*256 = 50176 >= 50000 node-pairs
#define CAP 16384              // per-bucket global record capacity.
                               // worst case (100% live): 3.2M/256 = 12500 mean,
                               // +6 sigma ~ 13200 << 16384. shift = 14.

// ---------------------------------------------------------------------------
// Prep: (a) per-node argmax -> 4-bit element idx, packed 2 nodes/byte;
// (b) 100-entry pair table; (c) zero the 256 global bucket counters
// (ws is re-poisoned by the harness every iteration, so this must run
// every launch -- it does, same stream, before scatter).
// ---------------------------------------------------------------------------
__global__ __launch_bounds__(256) void prep_kernel(
    const float* __restrict__ node_attrs,
    const int* __restrict__ atomic_numbers,
    const float* __restrict__ covalent_radii,
    uint8_t* __restrict__ node_elem4,
    float4* __restrict__ pair_tab,
    unsigned int* __restrict__ g_cnt) {
  int i = blockIdx.x * 256 + threadIdx.x;   // byte index: nodes 2i, 2i+1

  if (blockIdx.x == 0) {
    if (threadIdx.x < N_PAIRS) {
      int t = threadIdx.x;
      int eu = t / N_ELEMS, ev = t % N_ELEMS;
      float Zuf = (float)atomic_numbers[eu];
      float Zvf = (float)atomic_numbers[ev];
      float a = 0.4543f * 0.529f / (powf(Zuf, 0.3f) + powf(Zvf, 0.3f));
      float rmax = covalent_radii[(int)Zuf] + covalent_radii[(int)Zvf];
      pair_tab[t] = make_float4(1.0f / a, 0.5f * 14.3996f * Zuf * Zvf,
                                rmax, 1.0f / rmax);
    }
    if (threadIdx.x < NB) g_cnt[threadIdx.x] = 0u;
  }

  if (i < N_ELEM4) {
    unsigned int packed = 0;
#pragma unroll
    for (int h = 0; h < 2; ++h) {
      int node = 2 * i + h;
      const float2* row = (const float2*)(node_attrs + (size_t)node * N_ELEMS);
      float best = -INFINITY;
      int bj = 0;
#pragma unroll
      for (int k = 0; k < 5; ++k) {
        float2 v = row[k];
        if (v.x > best) { best = v.x; bj = 2 * k; }
        if (v.y > best) { best = v.y; bj = 2 * k + 1; }
      }
      packed |= (unsigned int)bj << (h * 4);
    }
    node_elem4[i] = (uint8_t)packed;
  }
}

// ---------------------------------------------------------------------------
// Per-edge math. envelope(p=6): 1 - 28 r^6 + 48 r^7 - 21 r^8, masked x<r_max.
// Element indices from the nibble-packed LDS table. Division via v_rcp_f32
// (rel err ~2^-22; we truncate 9 mantissa bits in the record anyway).
// Returns exactly 0.0f for masked (dead) edges -> caller skips the record.
// ---------------------------------------------------------------------------
__device__ __forceinline__ float edge_val(float xi, int u, int v,
                                          const uint8_t* s_elem4,
                                          const float4* s_tab) {
  int eu = (s_elem4[u >> 1] >> ((u & 1) * 4)) & 0xF;
  int ev = (s_elem4[v >> 1] >> ((v & 1) * 4)) & 0xF;
  float4 tb = s_tab[eu * N_ELEMS + ev];
  float roa = xi * tb.x;
  float phi = 0.1818f  * __expf(-3.2f    * roa)
            + 0.5099f  * __expf(-0.9423f * roa)
            + 0.2802f  * __expf(-0.4028f * roa)
            + 0.02817f * __expf(-0.2016f * roa);
  float val = tb.y * phi * __builtin_amdgcn_rcpf(xi);
  float r  = xi * tb.w;
  float r2 = r * r;
  float r6 = r2 * r2 * r2;
  float env = 1.0f - 28.0f * r6 + 48.0f * r6 * r - 21.0f * r6 * r2;
  return (xi < tb.z) ? val * env : 0.0f;
}

// ---------------------------------------------------------------------------
// Phase 2 (R13): per-bucket GLOBAL regions replace the per-block sorted dump.
//   - dead edges (envelope mask, ~50%) produce no record at all
//   - LDS atomics still assign block-local per-bucket ranks (cheap)
//   - ONE global atomicAdd per (block,bucket) claims a contiguous slice of
//     records[b*CAP ...]; threads then store records directly to global.
// Deleted vs R12: s_rec (25 KB LDS), the wave-0 scan, the place+dump phases,
// and the dir array. Reduce now reads each bucket as one contiguous run.
// pk layout: bucket[29:22] | rank[21:9] | localid[8:0]   (rank < 8192)
// record: fp32 value with low 9 mantissa bits replaced by local node id
// ---------------------------------------------------------------------------
__global__ __launch_bounds__(SCAT_THREADS, 8) void scatter_kernel(
    const float* __restrict__ x,
    const int* __restrict__ edge_index,      // [2, E]
    const uint8_t* __restrict__ node_elem4,
    const float4* __restrict__ pair_tab,
    unsigned int* __restrict__ g_cnt,        // [NB]
    unsigned int* __restrict__ records) {    // [NB * CAP]
  __shared__ uint4        s_elem4_v[N_ELEM4 / 16];  // 50000 B
  __shared__ float4       s_tab[N_PAIRS];           //  1600 B
  __shared__ unsigned int s_cnt[NB];                //  1024 B
  __shared__ unsigned int s_goff[NB];               //  1024 B -> 53.6 KB total
  const uint8_t* s_elem4 = (const uint8_t*)s_elem4_v;

  int tid = threadIdx.x;

  // stage packed table (50 KB) + pair table into LDS, coalesced uint4 copies
  {
    const uint4* src = (const uint4*)node_elem4;
    for (int j = tid; j < N_ELEM4 / 16; j += SCAT_THREADS) s_elem4_v[j] = src[j];
  }
  if (tid < N_PAIRS) s_tab[tid] = pair_tab[tid];
  if (tid < NB) s_cnt[tid] = 0u;
  __syncthreads();

  float val[8];
  unsigned int pk[8];

#pragma unroll
  for (int k = 0; k < 2; ++k) {
    int gl = k * SCAT_THREADS + tid;          // local float4-group (< 1564)
    int g  = blockIdx.x * NGROUPS + gl;       // global float4-group
    bool ok = (gl < NGROUPS) && (g < NG4);
    int e = g * 4;
    float4 xv = make_float4(1, 1, 1, 1);
    int4 uu = make_int4(0, 0, 0, 0), vv = make_int4(0, 0, 0, 0);
    if (ok) {
      xv = *(const float4*)(x + e);
      uu = *(const int4*)(edge_index + e);
      vv = *(const int4*)(edge_index + N_EDGES + e);
    }
    int rv[4] = {vv.x, vv.y, vv.z, vv.w};
    int ru[4] = {uu.x, uu.y, uu.z, uu.w};
    float xs[4] = {xv.x, xv.y, xv.z, xv.w};
#pragma unroll
    for (int c = 0; c < 4; ++c) {
      int j = k * 4 + c;
      pk[j] = 0xFFFFFFFFu;
      if (ok) {
        float v = edge_val(xs[c], ru[c], rv[c], s_elem4, s_tab);
        if (v != 0.0f) {                       // zero-skip: +0 never changes a sum
          unsigned int b = (unsigned int)rv[c] / NPB;
          unsigned int lid = (unsigned int)rv[c] - b * NPB;
          unsigned int r = atomicAdd(&s_cnt[b], 1u);   // block-local rank
          pk[j] = (b << 22) | (r << 9) | lid;
          val[j] = v;
        }
      }
    }
  }
  __syncthreads();

  // one global atomic per (block,bucket): claim slice of bucket b's region
  if (tid < NB) s_goff[tid] = atomicAdd(&g_cnt[tid], s_cnt[tid]);
  __syncthreads();

  // direct global stores: region[b] + goff[b] + rank  (scattered 4B, but
  // total live-record traffic is only ~6.5 MB through L2)
#pragma unroll
  for (int j = 0; j < 8; ++j) {
    if (pk[j] != 0xFFFFFFFFu) {
      unsigned int b = pk[j] >> 22;
      unsigned int r = (pk[j] >> 9) & 0x1FFFu;
      records[((size_t)b << 14) + s_goff[b] + r] =
          (__float_as_uint(val[j]) & ~0x1FFu) | (pk[j] & 0x1FFu);
    }
  }
}

// ---------------------------------------------------------------------------
// Phase 3: one 1024-thread block per bucket reads its region as ONE
// contiguous, fully-coalesced run of g_cnt[b] records (~6 iters/thread),
// LDS float atomics into 391 bins, coalesced store (writes every out
// element -> no memset of the poisoned d_out needed).
// ---------------------------------------------------------------------------
__global__ __launch_bounds__(1024) void reduce_kernel(
    const unsigned int* __restrict__ g_cnt,
    const unsigned int* __restrict__ records,
    float* __restrict__ out) {
  __shared__ float bins[NPB];
  int b = blockIdx.x, tid = threadIdx.x;

  if (tid < NPB) bins[tid] = 0.0f;
  __syncthreads();

  unsigned int cnt = g_cnt[b];
  const unsigned int* rp = records + ((size_t)b << 14);
  for (unsigned int i = tid; i < cnt; i += 1024) {
    unsigned int rec = rp[i];
    atomicAdd(&bins[rec & 0x1FFu], __uint_as_float(rec & ~0x1FFu));
  }
  __syncthreads();

  int nb0 = b * NPB;
  if (tid < NPB && nb0 + tid < N_NODES) out[nb0 + tid] = bins[tid];
}

// ---------------------------------------------------------------------------
extern "C" void kernel_launch(void* const* d_in, const int* in_sizes, int n_in,
                              void* d_out, int out_size, void* d_ws, size_t ws_size,
                              hipStream_t stream) {
  const float* x              = (const float*)d_in[0];
  const float* node_attrs     = (const float*)d_in[1];
  const int*   edge_index     = (const int*)d_in[2];
  const int*   atomic_numbers = (const int*)d_in[3];
  const float* covalent_radii = (const float*)d_in[4];
  float* out = (float*)d_out;

  // ws layout (16B-aligned sections):
  //   records   uint [NB*CAP]    = 16,777,216 B  @ 0
  //   g_cnt     uint [NB]        =      1,024 B  @ 16,777,216
  //   pair_tab  float4[100]      =      1,600 B  @ 16,778,240
  //   node_elem4 uint8[N_ELEM4]  =     50,000 B  @ 16,779,840
  char* wsp = (char*)d_ws;
  unsigned int* records    = (unsigned int*)wsp;
  unsigned int* g_cnt      = (unsigned int*)(wsp + 16777216);
  float4*       pair_tab   = (float4*)(wsp + 16778240);
  uint8_t*      node_elem4 = (uint8_t*)(wsp + 16779840);

  prep_kernel<<<PREP_BLOCKS, 256, 0, stream>>>(
      node_attrs, atomic_numbers, covalent_radii, node_elem4, pair_tab, g_cnt);

  scatter_kernel<<<NBLK, SCAT_THREADS, 0, stream>>>(
      x, edge_index, node_elem4, pair_tab, g_cnt, records);

  reduce_kernel<<<NB, 1024, 0, stream>>>(g_cnt, records, out);
}